// Round 12
// baseline (288.480 us; speedup 1.0000x reference)
//
#include <hip/hip_runtime.h>
#include <hip/hip_bf16.h>

typedef __attribute__((ext_vector_type(8))) short short8;
typedef __attribute__((ext_vector_type(4))) float f32x4;
typedef __attribute__((ext_vector_type(2))) unsigned uint2v;

#define NB 2
#define SEQ 2048
#define DM 2048
#define NHEAD 16
#define HDIM 128

__device__ __forceinline__ unsigned short f2bf(float f) {
    unsigned u = __float_as_uint(f);
    u += 0x7fffu + ((u >> 16) & 1u);   // round-to-nearest-even (finite vals)
    return (unsigned short)(u >> 16);
}
__device__ __forceinline__ float bf2f(unsigned short h) {
    return __uint_as_float(((unsigned)h) << 16);
}
// packed f32x2 -> bf16x2 (low word = a). Compiler emits v_cvt_pk_bf16_f32.
__device__ __forceinline__ unsigned pk2bf(float a, float b) {
    __hip_bfloat162 h = __float22bfloat162_rn(make_float2(a, b));
    return *reinterpret_cast<unsigned*>(&h);
}
// async global->LDS, 16B per lane. LDS dest must be wave-uniform base;
// HW writes base + lane*16. Global src is per-lane.
__device__ __forceinline__ void gload16(const unsigned short* g, unsigned short* l) {
    __builtin_amdgcn_global_load_lds((const __attribute__((address_space(1))) void*)g,
                                     (__attribute__((address_space(3))) void*)l,
                                     16, 0, 0);
}

// f32 -> bf16 stream converter, two segments. n*8 elements each.
__global__ __launch_bounds__(256) void cvt_bf16(const float* __restrict__ a,
                                                unsigned short* __restrict__ oa, int na8,
                                                const float* __restrict__ b,
                                                unsigned short* __restrict__ ob, int nb8)
{
    const int t0 = blockIdx.x * 256 + threadIdx.x;
    const int stride = gridDim.x * 256;
    for (int i = t0; i < na8; i += stride) {
        const f32x4* src = (const f32x4*)(a + (size_t)i * 8);
        f32x4 lo = src[0], hi = src[1];
        short8 v;
#pragma unroll
        for (int j = 0; j < 4; ++j) { v[j] = (short)f2bf(lo[j]); v[j + 4] = (short)f2bf(hi[j]); }
        *(short8*)(oa + (size_t)i * 8) = v;
    }
    for (int i = t0; i < nb8; i += stride) {
        const f32x4* src = (const f32x4*)(b + (size_t)i * 8);
        f32x4 lo = src[0], hi = src[1];
        short8 v;
#pragma unroll
        for (int j = 0; j < 4; ++j) { v[j] = (short)f2bf(lo[j]); v[j + 4] = (short)f2bf(hi[j]); }
        *(short8*)(ob + (size_t)i * 8) = v;
    }
}

// C = A * B^T, both bf16 [rows][K] row-major. 128x128 tile, BK=32, 256 thr
// (4 waves 2x2). TRIPLE-buffered global_load_lds staging with counted
// vmcnt(4) + raw s_barrier (wait BEFORE barrier -> all waves' tile kt+1
// staged when any wave reads it). Depth-2 prefetch: stage(kt+2) at loop top
// gives each load ~2 iterations of cover; no vmcnt(0) drain in the loop.
// Hazards: slot (kt+2)%3 was last read at iter kt-1 (sealed by that
// barrier); tail iters (no new stage) use vmcnt(0).
// 1-D grid; block->XCD = bid%8; per-XCD 2-row x CPX-col L2 chunks.
// EPI==0: f32 store. EPI==1: QKV scatter+layouts with fused RoPE.
template<int EPI, int CPX>
__global__ __launch_bounds__(256) void gemm_m97(const unsigned short* __restrict__ A,
                                                const unsigned short* __restrict__ B,
                                                int K,
                                                unsigned short* __restrict__ qb,
                                                unsigned short* __restrict__ kb,
                                                unsigned short* __restrict__ vtb,
                                                const float* __restrict__ posp,
                                                float* __restrict__ outf)
{
    __shared__ unsigned short smem[24576];  // A slots [0,12288) B slots [12288,24576); epi reuse
    const int tid = threadIdx.x;
    const int lane = tid & 63, w = tid >> 6;
    const int wr = w >> 1, wc = w & 1;
    const int g = lane >> 4, fr = lane & 15;
    const int lr = lane >> 2, ls = lane & 3;     // staging: row-in-16, 16B slot
    // XCD-aware chunked mapping
    const int x = blockIdx.x & 7, t = blockIdx.x >> 3;
    const int rp = t / (2 * CPX), wi = t % (2 * CPX);
    const int bx = x * CPX + (wi % CPX), by = rp * 2 + wi / CPX;
    const int row0 = by * 128, col0 = bx * 128;

    auto stage = [&](int s, int kt) {
        const int k0 = kt * 32;
#pragma unroll
        for (int c = 0; c < 2; ++c) {
            const int r = c * 64 + w * 16;       // wave-uniform row base in tile
            gload16(A + (size_t)(row0 + r + lr) * K + k0 + ls * 8,
                    smem + s * 4096 + r * 32);
            gload16(B + (size_t)(col0 + r + lr) * K + k0 + ls * 8,
                    smem + 12288 + s * 4096 + r * 32);
        }
    };

    const f32x4 fz = {0.f, 0.f, 0.f, 0.f};
    f32x4 acc[4][4];
#pragma unroll
    for (int m = 0; m < 4; ++m)
#pragma unroll
        for (int n = 0; n < 4; ++n) acc[m][n] = fz;

    const int nk = K / 32;
    // prologue: stage tiles 0,1; drain tile 0 (leave tile 1's 4 loads in flight)
    stage(0, 0);
    stage(1, 1);
    asm volatile("s_waitcnt vmcnt(4)" ::: "memory");
    __builtin_amdgcn_sched_barrier(0);
    __builtin_amdgcn_s_barrier();
    __builtin_amdgcn_sched_barrier(0);

    int cur = 0;
    for (int kt = 0; kt < nk; ++kt) {
        if (kt + 2 < nk) stage((kt + 2) % 3, kt + 2);
        short8 af[4], bfv[4];
#pragma unroll
        for (int m = 0; m < 4; ++m)
            af[m] = *(const short8*)&smem[cur * 4096 + (wr * 64 + m * 16 + fr) * 32 + g * 8];
#pragma unroll
        for (int n = 0; n < 4; ++n)
            bfv[n] = *(const short8*)&smem[12288 + cur * 4096 + (wc * 64 + n * 16 + fr) * 32 + g * 8];
#pragma unroll
        for (int m = 0; m < 4; ++m)
#pragma unroll
            for (int n = 0; n < 4; ++n)
                acc[m][n] = __builtin_amdgcn_mfma_f32_16x16x32_bf16(
                    af[m], bfv[n], acc[m][n], 0, 0, 0);
        // counted wait BEFORE the barrier: tile kt+1 complete for all waves
        if (kt + 2 < nk) asm volatile("s_waitcnt vmcnt(4)" ::: "memory");
        else             asm volatile("s_waitcnt vmcnt(0)" ::: "memory");
        __builtin_amdgcn_sched_barrier(0);
        __builtin_amdgcn_s_barrier();
        __builtin_amdgcn_sched_barrier(0);
        cur = (cur == 2) ? 0 : cur + 1;
    }

    if constexpr (EPI == 0) {
#pragma unroll
        for (int m = 0; m < 4; ++m)
#pragma unroll
            for (int n = 0; n < 4; ++n)
#pragma unroll
                for (int r = 0; r < 4; ++r) {
                    int rr = row0 + wr * 64 + m * 16 + g * 4 + r;
                    int cc = col0 + wc * 64 + n * 16 + fr;
                    outf[(size_t)rr * 2048 + cc] = acc[m][n][r];
                }
    } else {
        const int which = col0 >> 11;        // 0=Q 1=K 2=V (uniform per block)
        const int hB = (col0 >> 7) & 15;     // head (uniform per block)
        const int nb_ = row0 >> 11;          // uniform per block
        const size_t hb = (size_t)(nb_ * NHEAD + hB) * ((size_t)SEQ * HDIM);
        const int l0 = row0 & 2047;
        if (which < 2) {
            // stash C-tile bf16 into smem[128][128], 16B-slot XOR (rl&7)
#pragma unroll
            for (int m = 0; m < 4; ++m)
#pragma unroll
                for (int n = 0; n < 4; ++n)
#pragma unroll
                    for (int r = 0; r < 4; ++r) {
                        int rl = wr * 64 + m * 16 + g * 4 + r;
                        int cl = wc * 64 + n * 16 + fr;
                        smem[rl * 128 + (cl ^ ((rl & 7) * 8))] = f2bf(acc[m][n][r]);
                    }
            __syncthreads();
            // row-coalesced RoPE readback: thread -> (row-in-16, 16B hd slot)
            unsigned short* dst = which ? kb : qb;
            const int rg = tid >> 4;
            const int s8 = (tid & 15) * 8;
            const float sgn = (s8 < 64) ? -1.f : 1.f;
#pragma unroll
            for (int j = 0; j < 8; ++j) {
                int rl = j * 16 + rg;
                int l = l0 + rl;
                int sw = (rl & 7) * 8;
                short8 own = *(const short8*)&smem[rl * 128 + (s8 ^ sw)];
                short8 par = *(const short8*)&smem[rl * 128 + ((s8 ^ 64) ^ sw)];
                const float* cp = posp + (size_t)l * HDIM + s8;
                const float* sp = cp + (size_t)SEQ * HDIM;
                f32x4 c0 = *(const f32x4*)cp, c1 = *(const f32x4*)(cp + 4);
                f32x4 s0 = *(const f32x4*)sp, s1 = *(const f32x4*)(sp + 4);
                short8 res;
#pragma unroll
                for (int e = 0; e < 8; ++e) {
                    float cc = (e < 4) ? c0[e & 3] : c1[e & 3];
                    float ss = (e < 4) ? s0[e & 3] : s1[e & 3];
                    float o = bf2f((unsigned short)own[e]);
                    float p = bf2f((unsigned short)par[e]);
                    res[e] = (short)f2bf(o * cc + sgn * p * ss);
                }
                *(short8*)(dst + hb + (size_t)l * HDIM + s8) = res;
            }
        } else {
            // V^T: 4 acc values = 4 consecutive l -> one 8B packed store
#pragma unroll
            for (int m = 0; m < 4; ++m)
#pragma unroll
                for (int n = 0; n < 4; ++n) {
                    int lb = l0 + wr * 64 + m * 16 + g * 4;
                    int cl = wc * 64 + n * 16 + fr;   // hd
                    uint2v v;
                    v[0] = pk2bf(acc[m][n][0], acc[m][n][1]);
                    v[1] = pk2bf(acc[m][n][2], acc[m][n][3]);
                    *(uint2v*)(vtb + hb + (size_t)cl * SEQ + lb) = v;
                }
        }
    }
}

// causal flash attention, swapped-QK^T, cooperative LDS-staged K/V, KVBLK=64.
// 512 blocks, ONE 128-row tile each (16 tiles x 32 heads), heavy tiles first,
// XCD head-pinning. (round-11 kernel, unchanged)
__global__ __launch_bounds__(256, 2) void attn_k(const unsigned short* __restrict__ Q,
                                                 const unsigned short* __restrict__ K,
                                                 const unsigned short* __restrict__ VT,
                                                 unsigned short* __restrict__ O)
{
    const int lb = blockIdx.x;            // 0..511
    const int xcd = lb & 7, idx = lb >> 3;
    const int nh = xcd * 4 + (idx & 3);   // heads grouped per XCD
    const int tile = 15 - (idx >> 2);     // heavy (long-loop) tiles first
    const int tid = threadIdx.x;
    const int w = tid >> 6, lane = tid & 63;
    const int g = lane >> 4, fr = lane & 15;
    const float scale = 0.08838834764831845f;  // 1/sqrt(128)

    const unsigned short* Qh = Q + (size_t)nh * SEQ * HDIM;
    const unsigned short* Kh = K + (size_t)nh * SEQ * HDIM;
    const unsigned short* Vh = VT + (size_t)nh * SEQ * HDIM;  // [128][SEQ]
    const int nb = nh >> 4, h = nh & 15;

    __shared__ unsigned short Kt[2][8192];  // [64 keys][128 d], 16B-slot XOR (row&7)
    __shared__ unsigned short Vt[2][8192];  // [128 d][64 keys], 16B-slot XOR (d&7)
    __shared__ unsigned Plds[4][576];       // per-wave P^T, 16 rows x 36 words

    auto stage = [&](int bf, int kbi) {
        const int key0 = kbi * 64;
#pragma unroll
        for (int c = 0; c < 4; ++c) {
            int r = c * 16 + (tid >> 4);              // K row (key 0..63)
            int sK = tid & 15;                        // 16B slot in 256B row
            gload16(Kh + (size_t)(key0 + r) * HDIM + 8 * (sK ^ (r & 7)),
                    &Kt[bf][c * 2048 + w * 512]);
            int d = c * 32 + (tid >> 3);              // V row (dim 0..127)
            int sV = tid & 7;                         // 16B slot in 128B row
            gload16(Vh + (size_t)d * SEQ + key0 + 8 * (sV ^ (d & 7)),
                    &Vt[bf][c * 2048 + w * 512]);
        }
    };

    const int qt = tile * 128 + w * 32;
    const int nkb_w = (qt + 31) >> 6;      // wave's inclusive 64-key bound
    const int nkb_blk = 2 * tile + 1;      // block-uniform bound

    short8 qf[2][4];
#pragma unroll
    for (int u = 0; u < 2; ++u)
#pragma unroll
        for (int kk = 0; kk < 4; ++kk)
            qf[u][kk] = *(const short8*)(Qh + (size_t)(qt + u * 16 + fr) * HDIM + kk * 32 + g * 8);

    const f32x4 fz = {0.f, 0.f, 0.f, 0.f};
    f32x4 oacc[2][8];
#pragma unroll
    for (int u = 0; u < 2; ++u)
#pragma unroll
        for (int f = 0; f < 8; ++f) oacc[u][f] = fz;
    float mrow[2] = {-3e38f, -3e38f}, lrow[2] = {0.f, 0.f};

    stage(0, 0);
    int buf = 0;
    __syncthreads();   // vmcnt(0) drained -> tile 0 ready

    for (int kbi = 0; kbi <= nkb_blk; ++kbi) {
        if (kbi < nkb_blk) stage(buf ^ 1, kbi + 1);

        if (kbi <= nkb_w) {
            const int key0 = kbi * 64;
            f32x4 s[2][4];
#pragma unroll
            for (int u = 0; u < 2; ++u)
#pragma unroll
                for (int hh = 0; hh < 4; ++hh) s[u][hh] = fz;

            __builtin_amdgcn_s_setprio(1);
#pragma unroll
            for (int hh = 0; hh < 4; ++hh) {
                short8 kfh[4];
#pragma unroll
                for (int kk = 0; kk < 4; ++kk)
                    kfh[kk] = *(const short8*)&Kt[buf][(hh * 16 + fr) * 128 + 8 * ((4 * kk + g) ^ (fr & 7))];
#pragma unroll
                for (int u = 0; u < 2; ++u)
#pragma unroll
                    for (int kk = 0; kk < 4; ++kk)
                        s[u][hh] = __builtin_amdgcn_mfma_f32_16x16x32_bf16(kfh[kk], qf[u][kk], s[u][hh], 0, 0, 0);
            }
            __builtin_amdgcn_s_setprio(0);

#pragma unroll
            for (int u = 0; u < 2; ++u) {
                const int q = qt + u * 16 + fr;
#pragma unroll
                for (int hh = 0; hh < 4; ++hh)
#pragma unroll
                    for (int r = 0; r < 4; ++r) {
                        int key = key0 + hh * 16 + 4 * g + r;
                        float v = s[u][hh][r] * scale;
                        s[u][hh][r] = (key <= q) ? v : -1e30f;
                    }
                float mx = -3e38f;
#pragma unroll
                for (int hh = 0; hh < 4; ++hh)
                    mx = fmaxf(mx, fmaxf(fmaxf(s[u][hh][0], s[u][hh][1]),
                                         fmaxf(s[u][hh][2], s[u][hh][3])));
                mx = fmaxf(mx, __shfl_xor(mx, 16, 64));
                mx = fmaxf(mx, __shfl_xor(mx, 32, 64));
                // defer-max (T13): only rescale when max grew past threshold
                if (!__all(mx <= mrow[u] + 8.f)) {
                    float mn = fmaxf(mrow[u], mx);
                    float al = __expf(mrow[u] - mn);
                    mrow[u] = mn;
                    lrow[u] *= al;
#pragma unroll
                    for (int f = 0; f < 8; ++f)
#pragma unroll
                        for (int r = 0; r < 4; ++r) oacc[u][f][r] *= al;
                }
                float pv[4][4];
                float ps = 0.f;
#pragma unroll
                for (int hh = 0; hh < 4; ++hh)
#pragma unroll
                    for (int r = 0; r < 4; ++r) {
                        float e = __expf(s[u][hh][r] - mrow[u]);
                        pv[hh][r] = e;
                        ps += e;
                    }
                ps += __shfl_xor(ps, 16, 64);
                ps += __shfl_xor(ps, 32, 64);
                lrow[u] += ps;
                // P^T bounce: word kw holds keys {2kw,2kw+1}; row q=fr
                unsigned* Pw = &Plds[w][0];
#pragma unroll
                for (int hh = 0; hh < 4; ++hh) {
                    Pw[fr * 36 + hh * 8 + 2 * g + 0] = pk2bf(pv[hh][0], pv[hh][1]);
                    Pw[fr * 36 + hh * 8 + 2 * g + 1] = pk2bf(pv[hh][2], pv[hh][3]);
                }
                asm volatile("s_waitcnt lgkmcnt(0)" ::: "memory");
                short8 pf0 = *(const short8*)&Pw[fr * 36 + g * 4];
                short8 pf1 = *(const short8*)&Pw[fr * 36 + 16 + g * 4];

                __builtin_amdgcn_s_setprio(1);
#pragma unroll
                for (int f = 0; f < 8; ++f) {
                    short8 vfa = *(const short8*)&Vt[buf][(f * 16 + fr) * 64 + 8 * (g ^ (fr & 7))];
                    short8 vfb = *(const short8*)&Vt[buf][(f * 16 + fr) * 64 + 8 * ((4 + g) ^ (fr & 7))];
                    oacc[u][f] = __builtin_amdgcn_mfma_f32_16x16x32_bf16(vfa, pf0, oacc[u][f], 0, 0, 0);
                    oacc[u][f] = __builtin_amdgcn_mfma_f32_16x16x32_bf16(vfb, pf1, oacc[u][f], 0, 0, 0);
                }
                __builtin_amdgcn_s_setprio(0);
            }
        }
        __syncthreads();   // staging of buf^1 complete; all reads of buf done
        buf ^= 1;
    }

    // epilogue: O^T layout -> lane (g,fr): q = qt+16u+fr, d = f*16+4g+r
#pragma unroll
    for (int u = 0; u < 2; ++u) {
        const float inv = 1.0f / lrow[u];
        const size_t obase = ((size_t)nb * SEQ + qt + u * 16 + fr) * DM + h * HDIM;
#pragma unroll
        for (int f = 0; f < 8; ++f) {
            uint2v v;
            v[0] = pk2bf(oacc[u][f][0] * inv, oacc[u][f][1] * inv);
            v[1] = pk2bf(oacc[u][f][2] * inv, oacc[u][f][3] * inv);
            *(uint2v*)(O + obase + f * 16 + 4 * g) = v;
        }
    }
}

extern "C" void kernel_launch(void* const* d_in, const int* in_sizes, int n_in,
                              void* d_out, int out_size, void* d_ws, size_t ws_size,
                              hipStream_t stream) {
    const float* x    = (const float*)d_in[0];   // [2,2048,2048]
    const float* pos  = (const float*)d_in[1];   // [2,2048,128]
    const float* wqkv = (const float*)d_in[2];   // [6144,2048]
    const float* wo   = (const float*)d_in[3];   // [2048,2048]
    float* out = (float*)d_out;

    const size_t HBUF = (size_t)NB * NHEAD * SEQ * HDIM;  // 8Mi elems = 16MiB
    unsigned short* qb   = (unsigned short*)d_ws;         // Q; later w_o bf16
    unsigned short* kbuf = qb + HBUF;
    unsigned short* vtb  = kbuf + HBUF;
    unsigned short* obx  = vtb + HBUF;        // x_bf16 during gemm1, then attn O
    unsigned short* wqkvbf = (unsigned short*)d_out;  // 24MiB scratch in d_out
                                              // (dead before gemm_m97 rewrites d_out)

    // 0) pre-convert x and w_qkv to bf16
    cvt_bf16<<<dim3(2048), 256, 0, stream>>>(x, obx, 1048576, wqkv, wqkvbf, 1572864);
    // 1) QKV projection (bf16 x bf16, triple-buffered gload_lds) + RoPE + scatter.
    gemm_m97<1, 6><<<dim3(1536), 256, 0, stream>>>(obx, wqkvbf, 2048, qb, kbuf, vtb, pos, nullptr);
    // 2) causal flash attention (KVBLK=64, one tile/block)
    attn_k<<<dim3(512), 256, 0, stream>>>(qb, kbuf, vtb, obx);
    // 3) convert w_o -> bf16 into qb (dead after attn)
    cvt_bf16<<<dim3(512), 256, 0, stream>>>(wo, qb, 524288, wo, qb, 0);
    // 4) output projection (bf16 x bf16, triple-buffered) -> f32 d_out.
    gemm_m97<0, 2><<<dim3(512), 256, 0, stream>>>(obx, qb, 2048, nullptr, nullptr, nullptr, nullptr, out);
}

// Round 13
// 282.114 us; speedup vs baseline: 1.0226x; 1.0226x over previous
//
#include <hip/hip_runtime.h>
#include <hip/hip_bf16.h>

typedef __attribute__((ext_vector_type(8))) short short8;
typedef __attribute__((ext_vector_type(4))) float f32x4;
typedef __attribute__((ext_vector_type(2))) unsigned uint2v;

#define NB 2
#define SEQ 2048
#define DM 2048
#define NHEAD 16
#define HDIM 128

__device__ __forceinline__ unsigned short f2bf(float f) {
    unsigned u = __float_as_uint(f);
    u += 0x7fffu + ((u >> 16) & 1u);   // round-to-nearest-even (finite vals)
    return (unsigned short)(u >> 16);
}
__device__ __forceinline__ float bf2f(unsigned short h) {
    return __uint_as_float(((unsigned)h) << 16);
}
// packed f32x2 -> bf16x2 (low word = a). Compiler emits v_cvt_pk_bf16_f32.
__device__ __forceinline__ unsigned pk2bf(float a, float b) {
    __hip_bfloat162 h = __float22bfloat162_rn(make_float2(a, b));
    return *reinterpret_cast<unsigned*>(&h);
}
// async global->LDS, 16B per lane. LDS dest must be wave-uniform base;
// HW writes base + lane*16. Global src is per-lane.
__device__ __forceinline__ void gload16(const unsigned short* g, unsigned short* l) {
    __builtin_amdgcn_global_load_lds((const __attribute__((address_space(1))) void*)g,
                                     (__attribute__((address_space(3))) void*)l,
                                     16, 0, 0);
}

// f32 -> bf16 stream converter, two segments. n*8 elements each.
__global__ __launch_bounds__(256) void cvt_bf16(const float* __restrict__ a,
                                                unsigned short* __restrict__ oa, int na8,
                                                const float* __restrict__ b,
                                                unsigned short* __restrict__ ob, int nb8)
{
    const int t0 = blockIdx.x * 256 + threadIdx.x;
    const int stride = gridDim.x * 256;
    for (int i = t0; i < na8; i += stride) {
        const f32x4* src = (const f32x4*)(a + (size_t)i * 8);
        f32x4 lo = src[0], hi = src[1];
        short8 v;
#pragma unroll
        for (int j = 0; j < 4; ++j) { v[j] = (short)f2bf(lo[j]); v[j + 4] = (short)f2bf(hi[j]); }
        *(short8*)(oa + (size_t)i * 8) = v;
    }
    for (int i = t0; i < nb8; i += stride) {
        const f32x4* src = (const f32x4*)(b + (size_t)i * 8);
        f32x4 lo = src[0], hi = src[1];
        short8 v;
#pragma unroll
        for (int j = 0; j < 4; ++j) { v[j] = (short)f2bf(lo[j]); v[j + 4] = (short)f2bf(hi[j]); }
        *(short8*)(ob + (size_t)i * 8) = v;
    }
}

// C = A * B^T, both bf16 [rows][K] row-major. 128x128 tile, BK=32, 256 thr
// (4 waves 2x2), global_load_lds w=16 staging, 1 barrier/K-step (m97 form,
// round-11 proven variant). 1-D grid; block->XCD = bid%8; per-XCD 2-row x
// CPX-col L2 chunks. EPI==0: f32 store. EPI==1: QKV scatter + fused RoPE.
//   Q/K: LDS stash (XOR-swizzled) -> row-coalesced RoPE readback, 16B stores.
//   V:   direct 8B packed stores (4 consecutive l per acc vector).
template<int EPI, int CPX>
__global__ __launch_bounds__(256) void gemm_m97(const unsigned short* __restrict__ A,
                                                const unsigned short* __restrict__ B,
                                                int K,
                                                unsigned short* __restrict__ qb,
                                                unsigned short* __restrict__ kb,
                                                unsigned short* __restrict__ vtb,
                                                const float* __restrict__ posp,
                                                float* __restrict__ outf)
{
    __shared__ unsigned short smem[16384];  // At[2][4096] | Bt[2][4096]; epi reuse [128][128]
    const int tid = threadIdx.x;
    const int lane = tid & 63, w = tid >> 6;
    const int wr = w >> 1, wc = w & 1;
    const int g = lane >> 4, fr = lane & 15;
    const int lr = lane >> 2, ls = lane & 3;     // staging: row-in-16, 16B slot
    // XCD-aware chunked mapping
    const int x = blockIdx.x & 7, t = blockIdx.x >> 3;
    const int rp = t / (2 * CPX), wi = t % (2 * CPX);
    const int bx = x * CPX + (wi % CPX), by = rp * 2 + wi / CPX;
    const int row0 = by * 128, col0 = bx * 128;

    auto stage = [&](int b, int kt) {
        const int k0 = kt * 32;
#pragma unroll
        for (int c = 0; c < 2; ++c) {
            const int r = c * 64 + w * 16;       // wave-uniform row base in tile
            gload16(A + (size_t)(row0 + r + lr) * K + k0 + ls * 8,
                    smem + b * 4096 + r * 32);
            gload16(B + (size_t)(col0 + r + lr) * K + k0 + ls * 8,
                    smem + 8192 + b * 4096 + r * 32);
        }
    };

    const f32x4 fz = {0.f, 0.f, 0.f, 0.f};
    f32x4 acc[4][4];
#pragma unroll
    for (int m = 0; m < 4; ++m)
#pragma unroll
        for (int n = 0; n < 4; ++n) acc[m][n] = fz;

    const int nk = K / 32;
    stage(0, 0);
    __syncthreads();   // vmcnt(0) drained -> tile 0 ready
    for (int kt = 0; kt < nk; ++kt) {
        const int cur = kt & 1;
        if (kt + 1 < nk) stage(cur ^ 1, kt + 1);
        short8 af[4], bfv[4];
#pragma unroll
        for (int m = 0; m < 4; ++m)
            af[m] = *(const short8*)&smem[cur * 4096 + (wr * 64 + m * 16 + fr) * 32 + g * 8];
#pragma unroll
        for (int n = 0; n < 4; ++n)
            bfv[n] = *(const short8*)&smem[8192 + cur * 4096 + (wc * 64 + n * 16 + fr) * 32 + g * 8];
#pragma unroll
        for (int m = 0; m < 4; ++m)
#pragma unroll
            for (int n = 0; n < 4; ++n)
                acc[m][n] = __builtin_amdgcn_mfma_f32_16x16x32_bf16(
                    af[m], bfv[n], acc[m][n], 0, 0, 0);
        __syncthreads();   // reads of cur done; staging of cur^1 landed
    }

    if constexpr (EPI == 0) {
#pragma unroll
        for (int m = 0; m < 4; ++m)
#pragma unroll
            for (int n = 0; n < 4; ++n)
#pragma unroll
                for (int r = 0; r < 4; ++r) {
                    int rr = row0 + wr * 64 + m * 16 + g * 4 + r;
                    int cc = col0 + wc * 64 + n * 16 + fr;
                    outf[(size_t)rr * 2048 + cc] = acc[m][n][r];
                }
    } else {
        const int which = col0 >> 11;        // 0=Q 1=K 2=V (uniform per block)
        const int hB = (col0 >> 7) & 15;     // head (uniform per block)
        const int nb_ = row0 >> 11;          // uniform per block
        const size_t hb = (size_t)(nb_ * NHEAD + hB) * ((size_t)SEQ * HDIM);
        const int l0 = row0 & 2047;
        if (which < 2) {
            // stash C-tile bf16 into smem[128][128], 16B-slot XOR (rl&7)
#pragma unroll
            for (int m = 0; m < 4; ++m)
#pragma unroll
                for (int n = 0; n < 4; ++n)
#pragma unroll
                    for (int r = 0; r < 4; ++r) {
                        int rl = wr * 64 + m * 16 + g * 4 + r;
                        int cl = wc * 64 + n * 16 + fr;
                        smem[rl * 128 + (cl ^ ((rl & 7) * 8))] = f2bf(acc[m][n][r]);
                    }
            __syncthreads();
            // row-coalesced RoPE readback: thread -> (row-in-16, 16B hd slot)
            unsigned short* dst = which ? kb : qb;
            const int rg = tid >> 4;
            const int s8 = (tid & 15) * 8;
            const float sgn = (s8 < 64) ? -1.f : 1.f;
#pragma unroll
            for (int j = 0; j < 8; ++j) {
                int rl = j * 16 + rg;
                int l = l0 + rl;
                int sw = (rl & 7) * 8;
                short8 own = *(const short8*)&smem[rl * 128 + (s8 ^ sw)];
                short8 par = *(const short8*)&smem[rl * 128 + ((s8 ^ 64) ^ sw)];
                const float* cp = posp + (size_t)l * HDIM + s8;
                const float* sp = cp + (size_t)SEQ * HDIM;
                f32x4 c0 = *(const f32x4*)cp, c1 = *(const f32x4*)(cp + 4);
                f32x4 s0 = *(const f32x4*)sp, s1 = *(const f32x4*)(sp + 4);
                short8 res;
#pragma unroll
                for (int e = 0; e < 8; ++e) {
                    float cc = (e < 4) ? c0[e & 3] : c1[e & 3];
                    float ss = (e < 4) ? s0[e & 3] : s1[e & 3];
                    float o = bf2f((unsigned short)own[e]);
                    float p = bf2f((unsigned short)par[e]);
                    res[e] = (short)f2bf(o * cc + sgn * p * ss);
                }
                *(short8*)(dst + hb + (size_t)l * HDIM + s8) = res;
            }
        } else {
            // V^T: 4 acc values = 4 consecutive l -> one 8B packed store
#pragma unroll
            for (int m = 0; m < 4; ++m)
#pragma unroll
                for (int n = 0; n < 4; ++n) {
                    int lb = l0 + wr * 64 + m * 16 + g * 4;
                    int cl = wc * 64 + n * 16 + fr;   // hd
                    uint2v v;
                    v[0] = pk2bf(acc[m][n][0], acc[m][n][1]);
                    v[1] = pk2bf(acc[m][n][2], acc[m][n][3]);
                    *(uint2v*)(vtb + hb + (size_t)cl * SEQ + lb) = v;
                }
        }
    }
}

// causal flash attention, swapped-QK^T, cooperative LDS-staged K/V, KVBLK=64.
// LOAD BALANCE (r13): blocks lb and lb+256 co-reside on one CU (bid%8->XCD,
// (bid>>3)%32->CU round-robin). Map half 0 -> tile 15-j, half 1 -> tile j so
// each CU's pair sums to a constant 34 iterations (was 48 vs 18, 2.6x skew).
__global__ __launch_bounds__(256, 2) void attn_k(const unsigned short* __restrict__ Q,
                                                 const unsigned short* __restrict__ K,
                                                 const unsigned short* __restrict__ VT,
                                                 unsigned short* __restrict__ O)
{
    const int lb = blockIdx.x;            // 0..511
    const int half = lb >> 8;             // 0 or 1
    const int r0 = lb & 255;
    const int xcd = r0 & 7, idx = r0 >> 3;
    const int nh = xcd * 4 + (idx & 3);   // heads grouped per XCD
    const int j = idx >> 2;               // 0..7
    const int tile = half ? j : (15 - j); // anti-correlated pairing
    const int tid = threadIdx.x;
    const int w = tid >> 6, lane = tid & 63;
    const int g = lane >> 4, fr = lane & 15;
    const float scale = 0.08838834764831845f;  // 1/sqrt(128)

    const unsigned short* Qh = Q + (size_t)nh * SEQ * HDIM;
    const unsigned short* Kh = K + (size_t)nh * SEQ * HDIM;
    const unsigned short* Vh = VT + (size_t)nh * SEQ * HDIM;  // [128][SEQ]
    const int nb = nh >> 4, h = nh & 15;

    __shared__ unsigned short Kt[2][8192];  // [64 keys][128 d], 16B-slot XOR (row&7)
    __shared__ unsigned short Vt[2][8192];  // [128 d][64 keys], 16B-slot XOR (d&7)
    __shared__ unsigned Plds[4][576];       // per-wave P^T, 16 rows x 36 words

    auto stage = [&](int bf, int kbi) {
        const int key0 = kbi * 64;
#pragma unroll
        for (int c = 0; c < 4; ++c) {
            int r = c * 16 + (tid >> 4);              // K row (key 0..63)
            int sK = tid & 15;                        // 16B slot in 256B row
            gload16(Kh + (size_t)(key0 + r) * HDIM + 8 * (sK ^ (r & 7)),
                    &Kt[bf][c * 2048 + w * 512]);
            int d = c * 32 + (tid >> 3);              // V row (dim 0..127)
            int sV = tid & 7;                         // 16B slot in 128B row
            gload16(Vh + (size_t)d * SEQ + key0 + 8 * (sV ^ (d & 7)),
                    &Vt[bf][c * 2048 + w * 512]);
        }
    };

    const int qt = tile * 128 + w * 32;
    const int nkb_w = (qt + 31) >> 6;      // wave's inclusive 64-key bound
    const int nkb_blk = 2 * tile + 1;      // block-uniform bound

    short8 qf[2][4];
#pragma unroll
    for (int u = 0; u < 2; ++u)
#pragma unroll
        for (int kk = 0; kk < 4; ++kk)
            qf[u][kk] = *(const short8*)(Qh + (size_t)(qt + u * 16 + fr) * HDIM + kk * 32 + g * 8);

    const f32x4 fz = {0.f, 0.f, 0.f, 0.f};
    f32x4 oacc[2][8];
#pragma unroll
    for (int u = 0; u < 2; ++u)
#pragma unroll
        for (int f = 0; f < 8; ++f) oacc[u][f] = fz;
    float mrow[2] = {-3e38f, -3e38f}, lrow[2] = {0.f, 0.f};

    stage(0, 0);
    int buf = 0;
    __syncthreads();   // vmcnt(0) drained -> tile 0 ready

    for (int kbi = 0; kbi <= nkb_blk; ++kbi) {
        if (kbi < nkb_blk) stage(buf ^ 1, kbi + 1);

        if (kbi <= nkb_w) {
            const int key0 = kbi * 64;
            f32x4 s[2][4];
#pragma unroll
            for (int u = 0; u < 2; ++u)
#pragma unroll
                for (int hh = 0; hh < 4; ++hh) s[u][hh] = fz;

            __builtin_amdgcn_s_setprio(1);
#pragma unroll
            for (int hh = 0; hh < 4; ++hh) {
                short8 kfh[4];
#pragma unroll
                for (int kk = 0; kk < 4; ++kk)
                    kfh[kk] = *(const short8*)&Kt[buf][(hh * 16 + fr) * 128 + 8 * ((4 * kk + g) ^ (fr & 7))];
#pragma unroll
                for (int u = 0; u < 2; ++u)
#pragma unroll
                    for (int kk = 0; kk < 4; ++kk)
                        s[u][hh] = __builtin_amdgcn_mfma_f32_16x16x32_bf16(kfh[kk], qf[u][kk], s[u][hh], 0, 0, 0);
            }
            __builtin_amdgcn_s_setprio(0);

#pragma unroll
            for (int u = 0; u < 2; ++u) {
                const int q = qt + u * 16 + fr;
#pragma unroll
                for (int hh = 0; hh < 4; ++hh)
#pragma unroll
                    for (int r = 0; r < 4; ++r) {
                        int key = key0 + hh * 16 + 4 * g + r;
                        float v = s[u][hh][r] * scale;
                        s[u][hh][r] = (key <= q) ? v : -1e30f;
                    }
                float mx = -3e38f;
#pragma unroll
                for (int hh = 0; hh < 4; ++hh)
                    mx = fmaxf(mx, fmaxf(fmaxf(s[u][hh][0], s[u][hh][1]),
                                         fmaxf(s[u][hh][2], s[u][hh][3])));
                mx = fmaxf(mx, __shfl_xor(mx, 16, 64));
                mx = fmaxf(mx, __shfl_xor(mx, 32, 64));
                // defer-max (T13): only rescale when max grew past threshold
                if (!__all(mx <= mrow[u] + 8.f)) {
                    float mn = fmaxf(mrow[u], mx);
                    float al = __expf(mrow[u] - mn);
                    mrow[u] = mn;
                    lrow[u] *= al;
#pragma unroll
                    for (int f = 0; f < 8; ++f)
#pragma unroll
                        for (int r = 0; r < 4; ++r) oacc[u][f][r] *= al;
                }
                float pv[4][4];
                float ps = 0.f;
#pragma unroll
                for (int hh = 0; hh < 4; ++hh)
#pragma unroll
                    for (int r = 0; r < 4; ++r) {
                        float e = __expf(s[u][hh][r] - mrow[u]);
                        pv[hh][r] = e;
                        ps += e;
                    }
                ps += __shfl_xor(ps, 16, 64);
                ps += __shfl_xor(ps, 32, 64);
                lrow[u] += ps;
                // P^T bounce: word kw holds keys {2kw,2kw+1}; row q=fr
                unsigned* Pw = &Plds[w][0];
#pragma unroll
                for (int hh = 0; hh < 4; ++hh) {
                    Pw[fr * 36 + hh * 8 + 2 * g + 0] = pk2bf(pv[hh][0], pv[hh][1]);
                    Pw[fr * 36 + hh * 8 + 2 * g + 1] = pk2bf(pv[hh][2], pv[hh][3]);
                }
                asm volatile("s_waitcnt lgkmcnt(0)" ::: "memory");
                short8 pf0 = *(const short8*)&Pw[fr * 36 + g * 4];
                short8 pf1 = *(const short8*)&Pw[fr * 36 + 16 + g * 4];

                __builtin_amdgcn_s_setprio(1);
#pragma unroll
                for (int f = 0; f < 8; ++f) {
                    short8 vfa = *(const short8*)&Vt[buf][(f * 16 + fr) * 64 + 8 * (g ^ (fr & 7))];
                    short8 vfb = *(const short8*)&Vt[buf][(f * 16 + fr) * 64 + 8 * ((4 + g) ^ (fr & 7))];
                    oacc[u][f] = __builtin_amdgcn_mfma_f32_16x16x32_bf16(vfa, pf0, oacc[u][f], 0, 0, 0);
                    oacc[u][f] = __builtin_amdgcn_mfma_f32_16x16x32_bf16(vfb, pf1, oacc[u][f], 0, 0, 0);
                }
                __builtin_amdgcn_s_setprio(0);
            }
        }
        __syncthreads();   // staging of buf^1 complete; all reads of buf done
        buf ^= 1;
    }

    // epilogue: O^T layout -> lane (g,fr): q = qt+16u+fr, d = f*16+4g+r
#pragma unroll
    for (int u = 0; u < 2; ++u) {
        const float inv = 1.0f / lrow[u];
        const size_t obase = ((size_t)nb * SEQ + qt + u * 16 + fr) * DM + h * HDIM;
#pragma unroll
        for (int f = 0; f < 8; ++f) {
            uint2v v;
            v[0] = pk2bf(oacc[u][f][0] * inv, oacc[u][f][1] * inv);
            v[1] = pk2bf(oacc[u][f][2] * inv, oacc[u][f][3] * inv);
            *(uint2v*)(O + obase + f * 16 + 4 * g) = v;
        }
    }
}

extern "C" void kernel_launch(void* const* d_in, const int* in_sizes, int n_in,
                              void* d_out, int out_size, void* d_ws, size_t ws_size,
                              hipStream_t stream) {
    const float* x    = (const float*)d_in[0];   // [2,2048,2048]
    const float* pos  = (const float*)d_in[1];   // [2,2048,128]
    const float* wqkv = (const float*)d_in[2];   // [6144,2048]
    const float* wo   = (const float*)d_in[3];   // [2048,2048]
    float* out = (float*)d_out;

    const size_t HBUF = (size_t)NB * NHEAD * SEQ * HDIM;  // 8Mi elems = 16MiB
    unsigned short* qb   = (unsigned short*)d_ws;         // Q; later w_o bf16
    unsigned short* kbuf = qb + HBUF;
    unsigned short* vtb  = kbuf + HBUF;
    unsigned short* obx  = vtb + HBUF;        // x_bf16 during gemm1, then attn O
    unsigned short* wqkvbf = (unsigned short*)d_out;  // 24MiB scratch in d_out
                                              // (dead before gemm_m97 rewrites d_out)

    // 0) pre-convert x and w_qkv to bf16
    cvt_bf16<<<dim3(2048), 256, 0, stream>>>(x, obx, 1048576, wqkv, wqkvbf, 1572864);
    // 1) QKV projection (bf16 x bf16, gload_lds double-buffer) + RoPE + scatter.
    gemm_m97<1, 6><<<dim3(1536), 256, 0, stream>>>(obx, wqkvbf, 2048, qb, kbuf, vtb, pos, nullptr);
    // 2) causal flash attention (KVBLK=64, balanced tile pairing)
    attn_k<<<dim3(512), 256, 0, stream>>>(qb, kbuf, vtb, obx);
    // 3) convert w_o -> bf16 into qb (dead after attn)
    cvt_bf16<<<dim3(512), 256, 0, stream>>>(wo, qb, 524288, wo, qb, 0);
    // 4) output projection (bf16 x bf16) -> f32 d_out.
    gemm_m97<0, 2><<<dim3(512), 256, 0, stream>>>(obx, qb, 2048, nullptr, nullptr, nullptr, nullptr, out);
}

// Round 14
// 280.885 us; speedup vs baseline: 1.0270x; 1.0044x over previous
//
#include <hip/hip_runtime.h>
#include <hip/hip_bf16.h>

typedef __attribute__((ext_vector_type(8))) short short8;
typedef __attribute__((ext_vector_type(4))) float f32x4;
typedef __attribute__((ext_vector_type(2))) unsigned uint2v;

#define NB 2
#define SEQ 2048
#define DM 2048
#define NHEAD 16
#define HDIM 128

__device__ __forceinline__ unsigned short f2bf(float f) {
    unsigned u = __float_as_uint(f);
    u += 0x7fffu + ((u >> 16) & 1u);   // round-to-nearest-even (finite vals)
    return (unsigned short)(u >> 16);
}
__device__ __forceinline__ float bf2f(unsigned short h) {
    return __uint_as_float(((unsigned)h) << 16);
}
// packed f32x2 -> bf16x2 (low word = a). Compiler emits v_cvt_pk_bf16_f32.
__device__ __forceinline__ unsigned pk2bf(float a, float b) {
    __hip_bfloat162 h = __float22bfloat162_rn(make_float2(a, b));
    return *reinterpret_cast<unsigned*>(&h);
}
// async global->LDS, 16B per lane. LDS dest must be wave-uniform base;
// HW writes base + lane*16. Global src is per-lane.
__device__ __forceinline__ void gload16(const unsigned short* g, unsigned short* l) {
    __builtin_amdgcn_global_load_lds((const __attribute__((address_space(1))) void*)g,
                                     (__attribute__((address_space(3))) void*)l,
                                     16, 0, 0);
}

// f32 -> bf16 stream converter, two segments. n*8 elements each.
__global__ __launch_bounds__(256) void cvt_bf16(const float* __restrict__ a,
                                                unsigned short* __restrict__ oa, int na8,
                                                const float* __restrict__ b,
                                                unsigned short* __restrict__ ob, int nb8)
{
    const int t0 = blockIdx.x * 256 + threadIdx.x;
    const int stride = gridDim.x * 256;
    for (int i = t0; i < na8; i += stride) {
        const f32x4* src = (const f32x4*)(a + (size_t)i * 8);
        f32x4 lo = src[0], hi = src[1];
        short8 v;
#pragma unroll
        for (int j = 0; j < 4; ++j) { v[j] = (short)f2bf(lo[j]); v[j + 4] = (short)f2bf(hi[j]); }
        *(short8*)(oa + (size_t)i * 8) = v;
    }
    for (int i = t0; i < nb8; i += stride) {
        const f32x4* src = (const f32x4*)(b + (size_t)i * 8);
        f32x4 lo = src[0], hi = src[1];
        short8 v;
#pragma unroll
        for (int j = 0; j < 4; ++j) { v[j] = (short)f2bf(lo[j]); v[j + 4] = (short)f2bf(hi[j]); }
        *(short8*)(ob + (size_t)i * 8) = v;
    }
}

// C = A * B^T, both bf16 [rows][K] row-major. 128x128 tile, BK=32, 256 thr
// (4 waves 2x2), global_load_lds w=16 staging, 1 barrier/K-step (m97 form).
// 1-D grid; block->XCD = bid%8. Per XCD: CPX col-panels processed in CHALF
// sequential groups of CPX/CHALF (r14: shrinks L2 hot set; QKV 4MB->2.5MB),
// iterating 2-row x nsub-col chunks inside each group.
// EPI==0: f32 store. EPI==1: QKV scatter + fused RoPE.
template<int EPI, int CPX, int CHALF>
__global__ __launch_bounds__(256) void gemm_m97(const unsigned short* __restrict__ A,
                                                const unsigned short* __restrict__ B,
                                                int K,
                                                unsigned short* __restrict__ qb,
                                                unsigned short* __restrict__ kb,
                                                unsigned short* __restrict__ vtb,
                                                const float* __restrict__ posp,
                                                float* __restrict__ outf)
{
    __shared__ unsigned short smem[16384];  // At[2][4096] | Bt[2][4096]; epi reuse [128][128]
    const int tid = threadIdx.x;
    const int lane = tid & 63, w = tid >> 6;
    const int wr = w >> 1, wc = w & 1;
    const int g = lane >> 4, fr = lane & 15;
    const int lr = lane >> 2, ls = lane & 3;     // staging: row-in-16, 16B slot
    // XCD-aware chunked mapping with col-group split
    constexpr int NSUB = CPX / CHALF;
    const int x = blockIdx.x & 7, t = blockIdx.x >> 3;
    const int ch = t / (32 * NSUB), u = t % (32 * NSUB);
    const int rp = u / (2 * NSUB), wi = u % (2 * NSUB);
    const int bx = x * CPX + ch * NSUB + (wi % NSUB), by = rp * 2 + wi / NSUB;
    const int row0 = by * 128, col0 = bx * 128;

    auto stage = [&](int b, int kt) {
        const int k0 = kt * 32;
#pragma unroll
        for (int c = 0; c < 2; ++c) {
            const int r = c * 64 + w * 16;       // wave-uniform row base in tile
            gload16(A + (size_t)(row0 + r + lr) * K + k0 + ls * 8,
                    smem + b * 4096 + r * 32);
            gload16(B + (size_t)(col0 + r + lr) * K + k0 + ls * 8,
                    smem + 8192 + b * 4096 + r * 32);
        }
    };

    const f32x4 fz = {0.f, 0.f, 0.f, 0.f};
    f32x4 acc[4][4];
#pragma unroll
    for (int m = 0; m < 4; ++m)
#pragma unroll
        for (int n = 0; n < 4; ++n) acc[m][n] = fz;

    const int nk = K / 32;
    stage(0, 0);
    __syncthreads();   // vmcnt(0) drained -> tile 0 ready
    for (int kt = 0; kt < nk; ++kt) {
        const int cur = kt & 1;
        if (kt + 1 < nk) stage(cur ^ 1, kt + 1);
        short8 af[4], bfv[4];
#pragma unroll
        for (int m = 0; m < 4; ++m)
            af[m] = *(const short8*)&smem[cur * 4096 + (wr * 64 + m * 16 + fr) * 32 + g * 8];
#pragma unroll
        for (int n = 0; n < 4; ++n)
            bfv[n] = *(const short8*)&smem[8192 + cur * 4096 + (wc * 64 + n * 16 + fr) * 32 + g * 8];
#pragma unroll
        for (int m = 0; m < 4; ++m)
#pragma unroll
            for (int n = 0; n < 4; ++n)
                acc[m][n] = __builtin_amdgcn_mfma_f32_16x16x32_bf16(
                    af[m], bfv[n], acc[m][n], 0, 0, 0);
        __syncthreads();   // reads of cur done; staging of cur^1 landed
    }

    if constexpr (EPI == 0) {
#pragma unroll
        for (int m = 0; m < 4; ++m)
#pragma unroll
            for (int n = 0; n < 4; ++n)
#pragma unroll
                for (int r = 0; r < 4; ++r) {
                    int rr = row0 + wr * 64 + m * 16 + g * 4 + r;
                    int cc = col0 + wc * 64 + n * 16 + fr;
                    outf[(size_t)rr * 2048 + cc] = acc[m][n][r];
                }
    } else {
        const int which = col0 >> 11;        // 0=Q 1=K 2=V (uniform per block)
        const int hB = (col0 >> 7) & 15;     // head (uniform per block)
        const int nb_ = row0 >> 11;          // uniform per block
        const size_t hb = (size_t)(nb_ * NHEAD + hB) * ((size_t)SEQ * HDIM);
        const int l0 = row0 & 2047;
        if (which < 2) {
            // stash C-tile bf16 into smem[128][128], 16B-slot XOR (rl&7)
#pragma unroll
            for (int m = 0; m < 4; ++m)
#pragma unroll
                for (int n = 0; n < 4; ++n)
#pragma unroll
                    for (int r = 0; r < 4; ++r) {
                        int rl = wr * 64 + m * 16 + g * 4 + r;
                        int cl = wc * 64 + n * 16 + fr;
                        smem[rl * 128 + (cl ^ ((rl & 7) * 8))] = f2bf(acc[m][n][r]);
                    }
            __syncthreads();
            // row-coalesced RoPE readback: thread -> (row-in-16, 16B hd slot)
            unsigned short* dst = which ? kb : qb;
            const int rg = tid >> 4;
            const int s8 = (tid & 15) * 8;
            const float sgn = (s8 < 64) ? -1.f : 1.f;
#pragma unroll
            for (int j = 0; j < 8; ++j) {
                int rl = j * 16 + rg;
                int l = l0 + rl;
                int sw = (rl & 7) * 8;
                short8 own = *(const short8*)&smem[rl * 128 + (s8 ^ sw)];
                short8 par = *(const short8*)&smem[rl * 128 + ((s8 ^ 64) ^ sw)];
                const float* cp = posp + (size_t)l * HDIM + s8;
                const float* sp = cp + (size_t)SEQ * HDIM;
                f32x4 c0 = *(const f32x4*)cp, c1 = *(const f32x4*)(cp + 4);
                f32x4 s0 = *(const f32x4*)sp, s1 = *(const f32x4*)(sp + 4);
                short8 res;
#pragma unroll
                for (int e = 0; e < 8; ++e) {
                    float cc = (e < 4) ? c0[e & 3] : c1[e & 3];
                    float ss = (e < 4) ? s0[e & 3] : s1[e & 3];
                    float o = bf2f((unsigned short)own[e]);
                    float p = bf2f((unsigned short)par[e]);
                    res[e] = (short)f2bf(o * cc + sgn * p * ss);
                }
                *(short8*)(dst + hb + (size_t)l * HDIM + s8) = res;
            }
        } else {
            // V^T: 4 acc values = 4 consecutive l -> one 8B packed store
#pragma unroll
            for (int m = 0; m < 4; ++m)
#pragma unroll
                for (int n = 0; n < 4; ++n) {
                    int lb = l0 + wr * 64 + m * 16 + g * 4;
                    int cl = wc * 64 + n * 16 + fr;   // hd
                    uint2v v;
                    v[0] = pk2bf(acc[m][n][0], acc[m][n][1]);
                    v[1] = pk2bf(acc[m][n][2], acc[m][n][3]);
                    *(uint2v*)(vtb + hb + (size_t)cl * SEQ + lb) = v;
                }
        }
    }
}

// causal flash attention, swapped-QK^T, cooperative LDS-staged K/V, KVBLK=64.
// r14: 64-row q-tiles -> 1024 blocks (3 resident/CU, 12 waves vs 8) for
// latency hiding; wave w owns rows tile*64+w*16 (all waves share the same KV
// bound -> zero divergence). Anti-correlated tile quartets {31-j, j, 23-j,
// 8+j} keep each CU slot at a constant 66 iterations. XCD head-pinning kept.
__global__ __launch_bounds__(256, 2) void attn_k(const unsigned short* __restrict__ Q,
                                                 const unsigned short* __restrict__ K,
                                                 const unsigned short* __restrict__ VT,
                                                 unsigned short* __restrict__ O)
{
    const int lb = blockIdx.x;            // 0..1023
    const int quart = lb >> 8;            // 0..3
    const int r0 = lb & 255;
    const int xcd = r0 & 7, idx = r0 >> 3;
    const int nh = xcd * 4 + (idx & 3);   // heads grouped per XCD
    const int j = idx >> 2;               // 0..7
    const int tile = (quart == 0) ? (31 - j) : (quart == 1) ? j
                   : (quart == 2) ? (23 - j) : (8 + j);
    const int tid = threadIdx.x;
    const int w = tid >> 6, lane = tid & 63;
    const int g = lane >> 4, fr = lane & 15;
    const float scale = 0.08838834764831845f;  // 1/sqrt(128)

    const unsigned short* Qh = Q + (size_t)nh * SEQ * HDIM;
    const unsigned short* Kh = K + (size_t)nh * SEQ * HDIM;
    const unsigned short* Vh = VT + (size_t)nh * SEQ * HDIM;  // [128][SEQ]
    const int nb = nh >> 4, h = nh & 15;

    __shared__ unsigned short Kt[2][8192];  // [64 keys][128 d], 16B-slot XOR (row&7)
    __shared__ unsigned short Vt[2][8192];  // [128 d][64 keys], 16B-slot XOR (d&7)
    __shared__ unsigned Plds[4][576];       // per-wave P^T, 16 rows x 36 words

    auto stage = [&](int bf, int kbi) {
        const int key0 = kbi * 64;
#pragma unroll
        for (int c = 0; c < 4; ++c) {
            int r = c * 16 + (tid >> 4);              // K row (key 0..63)
            int sK = tid & 15;                        // 16B slot in 256B row
            gload16(Kh + (size_t)(key0 + r) * HDIM + 8 * (sK ^ (r & 7)),
                    &Kt[bf][c * 2048 + w * 512]);
            int d = c * 32 + (tid >> 3);              // V row (dim 0..127)
            int sV = tid & 7;                         // 16B slot in 128B row
            gload16(Vh + (size_t)d * SEQ + key0 + 8 * (sV ^ (d & 7)),
                    &Vt[bf][c * 2048 + w * 512]);
        }
    };

    const int qt = tile * 64 + w * 16;     // this wave's 16 q-rows
    const int nkb = tile;                  // inclusive KV bound (uniform!)

    short8 qf[4];
#pragma unroll
    for (int kk = 0; kk < 4; ++kk)
        qf[kk] = *(const short8*)(Qh + (size_t)(qt + fr) * HDIM + kk * 32 + g * 8);

    const f32x4 fz = {0.f, 0.f, 0.f, 0.f};
    f32x4 oacc[8];
#pragma unroll
    for (int f = 0; f < 8; ++f) oacc[f] = fz;
    float mrow = -3e38f, lrow = 0.f;

    stage(0, 0);
    int buf = 0;
    __syncthreads();   // vmcnt(0) drained -> tile 0 ready

    for (int kbi = 0; kbi <= nkb; ++kbi) {
        if (kbi < nkb) stage(buf ^ 1, kbi + 1);

        const int key0 = kbi * 64;
        f32x4 s[4];
#pragma unroll
        for (int hh = 0; hh < 4; ++hh) s[hh] = fz;

        __builtin_amdgcn_s_setprio(1);
#pragma unroll
        for (int hh = 0; hh < 4; ++hh) {
            short8 kfh[4];
#pragma unroll
            for (int kk = 0; kk < 4; ++kk)
                kfh[kk] = *(const short8*)&Kt[buf][(hh * 16 + fr) * 128 + 8 * ((4 * kk + g) ^ (fr & 7))];
#pragma unroll
            for (int kk = 0; kk < 4; ++kk)
                s[hh] = __builtin_amdgcn_mfma_f32_16x16x32_bf16(kfh[kk], qf[kk], s[hh], 0, 0, 0);
        }
        __builtin_amdgcn_s_setprio(0);

        const int q = qt + fr;
#pragma unroll
        for (int hh = 0; hh < 4; ++hh)
#pragma unroll
            for (int r = 0; r < 4; ++r) {
                int key = key0 + hh * 16 + 4 * g + r;
                float v = s[hh][r] * scale;
                s[hh][r] = (key <= q) ? v : -1e30f;
            }
        float mx = -3e38f;
#pragma unroll
        for (int hh = 0; hh < 4; ++hh)
            mx = fmaxf(mx, fmaxf(fmaxf(s[hh][0], s[hh][1]), fmaxf(s[hh][2], s[hh][3])));
        mx = fmaxf(mx, __shfl_xor(mx, 16, 64));
        mx = fmaxf(mx, __shfl_xor(mx, 32, 64));
        // defer-max (T13): only rescale when max grew past threshold
        if (!__all(mx <= mrow + 8.f)) {
            float mn = fmaxf(mrow, mx);
            float al = __expf(mrow - mn);
            mrow = mn;
            lrow *= al;
#pragma unroll
            for (int f = 0; f < 8; ++f)
#pragma unroll
                for (int r = 0; r < 4; ++r) oacc[f][r] *= al;
        }
        float pv[4][4];
        float ps = 0.f;
#pragma unroll
        for (int hh = 0; hh < 4; ++hh)
#pragma unroll
            for (int r = 0; r < 4; ++r) {
                float e = __expf(s[hh][r] - mrow);
                pv[hh][r] = e;
                ps += e;
            }
        ps += __shfl_xor(ps, 16, 64);
        ps += __shfl_xor(ps, 32, 64);
        lrow += ps;
        // P^T bounce: word kw holds keys {2kw,2kw+1}; row q=fr
        unsigned* Pw = &Plds[w][0];
#pragma unroll
        for (int hh = 0; hh < 4; ++hh) {
            Pw[fr * 36 + hh * 8 + 2 * g + 0] = pk2bf(pv[hh][0], pv[hh][1]);
            Pw[fr * 36 + hh * 8 + 2 * g + 1] = pk2bf(pv[hh][2], pv[hh][3]);
        }
        asm volatile("s_waitcnt lgkmcnt(0)" ::: "memory");
        short8 pf0 = *(const short8*)&Pw[fr * 36 + g * 4];
        short8 pf1 = *(const short8*)&Pw[fr * 36 + 16 + g * 4];

        __builtin_amdgcn_s_setprio(1);
#pragma unroll
        for (int f = 0; f < 8; ++f) {
            short8 vfa = *(const short8*)&Vt[buf][(f * 16 + fr) * 64 + 8 * (g ^ (fr & 7))];
            short8 vfb = *(const short8*)&Vt[buf][(f * 16 + fr) * 64 + 8 * ((4 + g) ^ (fr & 7))];
            oacc[f] = __builtin_amdgcn_mfma_f32_16x16x32_bf16(vfa, pf0, oacc[f], 0, 0, 0);
            oacc[f] = __builtin_amdgcn_mfma_f32_16x16x32_bf16(vfb, pf1, oacc[f], 0, 0, 0);
        }
        __builtin_amdgcn_s_setprio(0);

        __syncthreads();   // staging of buf^1 complete; all reads of buf done
        buf ^= 1;
    }

    // epilogue: O^T layout -> lane (g,fr): q = qt+fr, d = f*16+4g+r
    const float inv = 1.0f / lrow;
    const size_t obase = ((size_t)nb * SEQ + qt + fr) * DM + h * HDIM;
#pragma unroll
    for (int f = 0; f < 8; ++f) {
        uint2v v;
        v[0] = pk2bf(oacc[f][0] * inv, oacc[f][1] * inv);
        v[1] = pk2bf(oacc[f][2] * inv, oacc[f][3] * inv);
        *(uint2v*)(O + obase + f * 16 + 4 * g) = v;
    }
}

extern "C" void kernel_launch(void* const* d_in, const int* in_sizes, int n_in,
                              void* d_out, int out_size, void* d_ws, size_t ws_size,
                              hipStream_t stream) {
    const float* x    = (const float*)d_in[0];   // [2,2048,2048]
    const float* pos  = (const float*)d_in[1];   // [2,2048,128]
    const float* wqkv = (const float*)d_in[2];   // [6144,2048]
    const float* wo   = (const float*)d_in[3];   // [2048,2048]
    float* out = (float*)d_out;

    const size_t HBUF = (size_t)NB * NHEAD * SEQ * HDIM;  // 8Mi elems = 16MiB
    unsigned short* qb   = (unsigned short*)d_ws;         // Q; later w_o bf16
    unsigned short* kbuf = qb + HBUF;
    unsigned short* vtb  = kbuf + HBUF;
    unsigned short* obx  = vtb + HBUF;        // x_bf16 during gemm1, then attn O
    unsigned short* wqkvbf = (unsigned short*)d_out;  // 24MiB scratch in d_out
                                              // (dead before gemm_m97 rewrites d_out)

    // 0) pre-convert x and w_qkv to bf16
    cvt_bf16<<<dim3(2048), 256, 0, stream>>>(x, obx, 1048576, wqkv, wqkvbf, 1572864);
    // 1) QKV projection (bf16 x bf16, gload_lds) + RoPE + head scatter.
    //    Per XCD: 2 col-groups of 3 panels (L2 hot set 2.5MB).
    gemm_m97<1, 6, 2><<<dim3(1536), 256, 0, stream>>>(obx, wqkvbf, 2048, qb, kbuf, vtb, pos, nullptr);
    // 2) causal flash attention (KVBLK=64, 64-row tiles, 1024 blocks)
    attn_k<<<dim3(1024), 256, 0, stream>>>(qb, kbuf, vtb, obx);
    // 3) convert w_o -> bf16 into qb (dead after attn)
    cvt_bf16<<<dim3(512), 256, 0, stream>>>(wo, qb, 524288, wo, qb, 0);
    // 4) output projection (bf16 x bf16) -> f32 d_out.
    gemm_m97<0, 2, 1><<<dim3(512), 256, 0, stream>>>(obx, qb, 2048, nullptr, nullptr, nullptr, nullptr, out);
}

// Round 15
// 279.535 us; speedup vs baseline: 1.0320x; 1.0048x over previous
//
#include <hip/hip_runtime.h>
#include <hip/hip_bf16.h>

typedef __attribute__((ext_vector_type(8))) short short8;
typedef __attribute__((ext_vector_type(4))) float f32x4;
typedef __attribute__((ext_vector_type(2))) unsigned uint2v;

#define NB 2
#define SEQ 2048
#define DM 2048
#define NHEAD 16
#define HDIM 128

__device__ __forceinline__ unsigned short f2bf(float f) {
    unsigned u = __float_as_uint(f);
    u += 0x7fffu + ((u >> 16) & 1u);   // round-to-nearest-even (finite vals)
    return (unsigned short)(u >> 16);
}
__device__ __forceinline__ float bf2f(unsigned short h) {
    return __uint_as_float(((unsigned)h) << 16);
}
// packed f32x2 -> bf16x2 (low word = a). Compiler emits v_cvt_pk_bf16_f32.
__device__ __forceinline__ unsigned pk2bf(float a, float b) {
    __hip_bfloat162 h = __float22bfloat162_rn(make_float2(a, b));
    return *reinterpret_cast<unsigned*>(&h);
}
// async global->LDS, 16B per lane. LDS dest must be wave-uniform base;
// HW writes base + lane*16. Global src is per-lane.
__device__ __forceinline__ void gload16(const unsigned short* g, unsigned short* l) {
    __builtin_amdgcn_global_load_lds((const __attribute__((address_space(1))) void*)g,
                                     (__attribute__((address_space(3))) void*)l,
                                     16, 0, 0);
}

// f32 -> bf16 stream converter, two segments. n*8 elements each.
__global__ __launch_bounds__(256) void cvt_bf16(const float* __restrict__ a,
                                                unsigned short* __restrict__ oa, int na8,
                                                const float* __restrict__ b,
                                                unsigned short* __restrict__ ob, int nb8)
{
    const int t0 = blockIdx.x * 256 + threadIdx.x;
    const int stride = gridDim.x * 256;
    for (int i = t0; i < na8; i += stride) {
        const f32x4* src = (const f32x4*)(a + (size_t)i * 8);
        f32x4 lo = src[0], hi = src[1];
        short8 v;
#pragma unroll
        for (int j = 0; j < 4; ++j) { v[j] = (short)f2bf(lo[j]); v[j + 4] = (short)f2bf(hi[j]); }
        *(short8*)(oa + (size_t)i * 8) = v;
    }
    for (int i = t0; i < nb8; i += stride) {
        const f32x4* src = (const f32x4*)(b + (size_t)i * 8);
        f32x4 lo = src[0], hi = src[1];
        short8 v;
#pragma unroll
        for (int j = 0; j < 4; ++j) { v[j] = (short)f2bf(lo[j]); v[j + 4] = (short)f2bf(hi[j]); }
        *(short8*)(ob + (size_t)i * 8) = v;
    }
}

// C = A * B^T, both bf16 [rows][K] row-major. 128x128 tile, BK=32, 256 thr
// (4 waves 2x2), global_load_lds w=16 staging, 1 barrier/K-step (m97 form).
// 1-D grid; block->XCD = bid%8. Per XCD: CPX col-panels, iterating 2-row x
// CPX-col chunks (CHALF=1; the r14 col-group split REGRESSED: A re-streamed
// per group, FETCH 102->155MB — keep CHALF=1).
// EPI==0: f32 store. EPI==1: QKV scatter + fused RoPE.
template<int EPI, int CPX, int CHALF>
__global__ __launch_bounds__(256) void gemm_m97(const unsigned short* __restrict__ A,
                                                const unsigned short* __restrict__ B,
                                                int K,
                                                unsigned short* __restrict__ qb,
                                                unsigned short* __restrict__ kb,
                                                unsigned short* __restrict__ vtb,
                                                const float* __restrict__ posp,
                                                float* __restrict__ outf)
{
    __shared__ unsigned short smem[16384];  // At[2][4096] | Bt[2][4096]; epi reuse [128][128]
    const int tid = threadIdx.x;
    const int lane = tid & 63, w = tid >> 6;
    const int wr = w >> 1, wc = w & 1;
    const int g = lane >> 4, fr = lane & 15;
    const int lr = lane >> 2, ls = lane & 3;     // staging: row-in-16, 16B slot
    // XCD-aware chunked mapping with col-group split
    constexpr int NSUB = CPX / CHALF;
    const int x = blockIdx.x & 7, t = blockIdx.x >> 3;
    const int ch = t / (32 * NSUB), u = t % (32 * NSUB);
    const int rp = u / (2 * NSUB), wi = u % (2 * NSUB);
    const int bx = x * CPX + ch * NSUB + (wi % NSUB), by = rp * 2 + wi / NSUB;
    const int row0 = by * 128, col0 = bx * 128;

    auto stage = [&](int b, int kt) {
        const int k0 = kt * 32;
#pragma unroll
        for (int c = 0; c < 2; ++c) {
            const int r = c * 64 + w * 16;       // wave-uniform row base in tile
            gload16(A + (size_t)(row0 + r + lr) * K + k0 + ls * 8,
                    smem + b * 4096 + r * 32);
            gload16(B + (size_t)(col0 + r + lr) * K + k0 + ls * 8,
                    smem + 8192 + b * 4096 + r * 32);
        }
    };

    const f32x4 fz = {0.f, 0.f, 0.f, 0.f};
    f32x4 acc[4][4];
#pragma unroll
    for (int m = 0; m < 4; ++m)
#pragma unroll
        for (int n = 0; n < 4; ++n) acc[m][n] = fz;

    const int nk = K / 32;
    stage(0, 0);
    __syncthreads();   // vmcnt(0) drained -> tile 0 ready
    for (int kt = 0; kt < nk; ++kt) {
        const int cur = kt & 1;
        if (kt + 1 < nk) stage(cur ^ 1, kt + 1);
        short8 af[4], bfv[4];
#pragma unroll
        for (int m = 0; m < 4; ++m)
            af[m] = *(const short8*)&smem[cur * 4096 + (wr * 64 + m * 16 + fr) * 32 + g * 8];
#pragma unroll
        for (int n = 0; n < 4; ++n)
            bfv[n] = *(const short8*)&smem[8192 + cur * 4096 + (wc * 64 + n * 16 + fr) * 32 + g * 8];
#pragma unroll
        for (int m = 0; m < 4; ++m)
#pragma unroll
            for (int n = 0; n < 4; ++n)
                acc[m][n] = __builtin_amdgcn_mfma_f32_16x16x32_bf16(
                    af[m], bfv[n], acc[m][n], 0, 0, 0);
        __syncthreads();   // reads of cur done; staging of cur^1 landed
    }

    if constexpr (EPI == 0) {
#pragma unroll
        for (int m = 0; m < 4; ++m)
#pragma unroll
            for (int n = 0; n < 4; ++n)
#pragma unroll
                for (int r = 0; r < 4; ++r) {
                    int rr = row0 + wr * 64 + m * 16 + g * 4 + r;
                    int cc = col0 + wc * 64 + n * 16 + fr;
                    outf[(size_t)rr * 2048 + cc] = acc[m][n][r];
                }
    } else {
        const int which = col0 >> 11;        // 0=Q 1=K 2=V (uniform per block)
        const int hB = (col0 >> 7) & 15;     // head (uniform per block)
        const int nb_ = row0 >> 11;          // uniform per block
        const size_t hb = (size_t)(nb_ * NHEAD + hB) * ((size_t)SEQ * HDIM);
        const int l0 = row0 & 2047;
        if (which < 2) {
            // stash C-tile bf16 into smem[128][128], 16B-slot XOR (rl&7)
#pragma unroll
            for (int m = 0; m < 4; ++m)
#pragma unroll
                for (int n = 0; n < 4; ++n)
#pragma unroll
                    for (int r = 0; r < 4; ++r) {
                        int rl = wr * 64 + m * 16 + g * 4 + r;
                        int cl = wc * 64 + n * 16 + fr;
                        smem[rl * 128 + (cl ^ ((rl & 7) * 8))] = f2bf(acc[m][n][r]);
                    }
            __syncthreads();
            // row-coalesced RoPE readback: thread -> (row-in-16, 16B hd slot)
            unsigned short* dst = which ? kb : qb;
            const int rg = tid >> 4;
            const int s8 = (tid & 15) * 8;
            const float sgn = (s8 < 64) ? -1.f : 1.f;
#pragma unroll
            for (int j = 0; j < 8; ++j) {
                int rl = j * 16 + rg;
                int l = l0 + rl;
                int sw = (rl & 7) * 8;
                short8 own = *(const short8*)&smem[rl * 128 + (s8 ^ sw)];
                short8 par = *(const short8*)&smem[rl * 128 + ((s8 ^ 64) ^ sw)];
                const float* cp = posp + (size_t)l * HDIM + s8;
                const float* sp = cp + (size_t)SEQ * HDIM;
                f32x4 c0 = *(const f32x4*)cp, c1 = *(const f32x4*)(cp + 4);
                f32x4 s0 = *(const f32x4*)sp, s1 = *(const f32x4*)(sp + 4);
                short8 res;
#pragma unroll
                for (int e = 0; e < 8; ++e) {
                    float cc = (e < 4) ? c0[e & 3] : c1[e & 3];
                    float ss = (e < 4) ? s0[e & 3] : s1[e & 3];
                    float o = bf2f((unsigned short)own[e]);
                    float p = bf2f((unsigned short)par[e]);
                    res[e] = (short)f2bf(o * cc + sgn * p * ss);
                }
                *(short8*)(dst + hb + (size_t)l * HDIM + s8) = res;
            }
        } else {
            // V^T: 4 acc values = 4 consecutive l -> one 8B packed store
#pragma unroll
            for (int m = 0; m < 4; ++m)
#pragma unroll
                for (int n = 0; n < 4; ++n) {
                    int lb = l0 + wr * 64 + m * 16 + g * 4;
                    int cl = wc * 64 + n * 16 + fr;   // hd
                    uint2v v;
                    v[0] = pk2bf(acc[m][n][0], acc[m][n][1]);
                    v[1] = pk2bf(acc[m][n][2], acc[m][n][3]);
                    *(uint2v*)(vtb + hb + (size_t)cl * SEQ + lb) = v;
                }
        }
    }
}

// causal flash attention, swapped-QK^T, cooperative LDS-staged K/V, KVBLK=64.
// 64-row q-tiles -> 1024 blocks (3 resident/CU, 12 waves) for latency hiding;
// wave w owns rows tile*64+w*16 (uniform KV bound -> zero divergence).
// Anti-correlated tile quartets {31-j, j, 23-j, 8+j} keep each CU slot at a
// constant 66 iterations. XCD head-pinning kept. (r14 kernel, unchanged)
__global__ __launch_bounds__(256, 2) void attn_k(const unsigned short* __restrict__ Q,
                                                 const unsigned short* __restrict__ K,
                                                 const unsigned short* __restrict__ VT,
                                                 unsigned short* __restrict__ O)
{
    const int lb = blockIdx.x;            // 0..1023
    const int quart = lb >> 8;            // 0..3
    const int r0 = lb & 255;
    const int xcd = r0 & 7, idx = r0 >> 3;
    const int nh = xcd * 4 + (idx & 3);   // heads grouped per XCD
    const int j = idx >> 2;               // 0..7
    const int tile = (quart == 0) ? (31 - j) : (quart == 1) ? j
                   : (quart == 2) ? (23 - j) : (8 + j);
    const int tid = threadIdx.x;
    const int w = tid >> 6, lane = tid & 63;
    const int g = lane >> 4, fr = lane & 15;
    const float scale = 0.08838834764831845f;  // 1/sqrt(128)

    const unsigned short* Qh = Q + (size_t)nh * SEQ * HDIM;
    const unsigned short* Kh = K + (size_t)nh * SEQ * HDIM;
    const unsigned short* Vh = VT + (size_t)nh * SEQ * HDIM;  // [128][SEQ]
    const int nb = nh >> 4, h = nh & 15;

    __shared__ unsigned short Kt[2][8192];  // [64 keys][128 d], 16B-slot XOR (row&7)
    __shared__ unsigned short Vt[2][8192];  // [128 d][64 keys], 16B-slot XOR (d&7)
    __shared__ unsigned Plds[4][576];       // per-wave P^T, 16 rows x 36 words

    auto stage = [&](int bf, int kbi) {
        const int key0 = kbi * 64;
#pragma unroll
        for (int c = 0; c < 4; ++c) {
            int r = c * 16 + (tid >> 4);              // K row (key 0..63)
            int sK = tid & 15;                        // 16B slot in 256B row
            gload16(Kh + (size_t)(key0 + r) * HDIM + 8 * (sK ^ (r & 7)),
                    &Kt[bf][c * 2048 + w * 512]);
            int d = c * 32 + (tid >> 3);              // V row (dim 0..127)
            int sV = tid & 7;                         // 16B slot in 128B row
            gload16(Vh + (size_t)d * SEQ + key0 + 8 * (sV ^ (d & 7)),
                    &Vt[bf][c * 2048 + w * 512]);
        }
    };

    const int qt = tile * 64 + w * 16;     // this wave's 16 q-rows
    const int nkb = tile;                  // inclusive KV bound (uniform!)

    short8 qf[4];
#pragma unroll
    for (int kk = 0; kk < 4; ++kk)
        qf[kk] = *(const short8*)(Qh + (size_t)(qt + fr) * HDIM + kk * 32 + g * 8);

    const f32x4 fz = {0.f, 0.f, 0.f, 0.f};
    f32x4 oacc[8];
#pragma unroll
    for (int f = 0; f < 8; ++f) oacc[f] = fz;
    float mrow = -3e38f, lrow = 0.f;

    stage(0, 0);
    int buf = 0;
    __syncthreads();   // vmcnt(0) drained -> tile 0 ready

    for (int kbi = 0; kbi <= nkb; ++kbi) {
        if (kbi < nkb) stage(buf ^ 1, kbi + 1);

        const int key0 = kbi * 64;
        f32x4 s[4];
#pragma unroll
        for (int hh = 0; hh < 4; ++hh) s[hh] = fz;

        __builtin_amdgcn_s_setprio(1);
#pragma unroll
        for (int hh = 0; hh < 4; ++hh) {
            short8 kfh[4];
#pragma unroll
            for (int kk = 0; kk < 4; ++kk)
                kfh[kk] = *(const short8*)&Kt[buf][(hh * 16 + fr) * 128 + 8 * ((4 * kk + g) ^ (fr & 7))];
#pragma unroll
            for (int kk = 0; kk < 4; ++kk)
                s[hh] = __builtin_amdgcn_mfma_f32_16x16x32_bf16(kfh[kk], qf[kk], s[hh], 0, 0, 0);
        }
        __builtin_amdgcn_s_setprio(0);

        const int q = qt + fr;
#pragma unroll
        for (int hh = 0; hh < 4; ++hh)
#pragma unroll
            for (int r = 0; r < 4; ++r) {
                int key = key0 + hh * 16 + 4 * g + r;
                float v = s[hh][r] * scale;
                s[hh][r] = (key <= q) ? v : -1e30f;
            }
        float mx = -3e38f;
#pragma unroll
        for (int hh = 0; hh < 4; ++hh)
            mx = fmaxf(mx, fmaxf(fmaxf(s[hh][0], s[hh][1]), fmaxf(s[hh][2], s[hh][3])));
        mx = fmaxf(mx, __shfl_xor(mx, 16, 64));
        mx = fmaxf(mx, __shfl_xor(mx, 32, 64));
        // defer-max (T13): only rescale when max grew past threshold
        if (!__all(mx <= mrow + 8.f)) {
            float mn = fmaxf(mrow, mx);
            float al = __expf(mrow - mn);
            mrow = mn;
            lrow *= al;
#pragma unroll
            for (int f = 0; f < 8; ++f)
#pragma unroll
                for (int r = 0; r < 4; ++r) oacc[f][r] *= al;
        }
        float pv[4][4];
        float ps = 0.f;
#pragma unroll
        for (int hh = 0; hh < 4; ++hh)
#pragma unroll
            for (int r = 0; r < 4; ++r) {
                float e = __expf(s[hh][r] - mrow);
                pv[hh][r] = e;
                ps += e;
            }
        ps += __shfl_xor(ps, 16, 64);
        ps += __shfl_xor(ps, 32, 64);
        lrow += ps;
        // P^T bounce: word kw holds keys {2kw,2kw+1}; row q=fr
        unsigned* Pw = &Plds[w][0];
#pragma unroll
        for (int hh = 0; hh < 4; ++hh) {
            Pw[fr * 36 + hh * 8 + 2 * g + 0] = pk2bf(pv[hh][0], pv[hh][1]);
            Pw[fr * 36 + hh * 8 + 2 * g + 1] = pk2bf(pv[hh][2], pv[hh][3]);
        }
        asm volatile("s_waitcnt lgkmcnt(0)" ::: "memory");
        short8 pf0 = *(const short8*)&Pw[fr * 36 + g * 4];
        short8 pf1 = *(const short8*)&Pw[fr * 36 + 16 + g * 4];

        __builtin_amdgcn_s_setprio(1);
#pragma unroll
        for (int f = 0; f < 8; ++f) {
            short8 vfa = *(const short8*)&Vt[buf][(f * 16 + fr) * 64 + 8 * (g ^ (fr & 7))];
            short8 vfb = *(const short8*)&Vt[buf][(f * 16 + fr) * 64 + 8 * ((4 + g) ^ (fr & 7))];
            oacc[f] = __builtin_amdgcn_mfma_f32_16x16x32_bf16(vfa, pf0, oacc[f], 0, 0, 0);
            oacc[f] = __builtin_amdgcn_mfma_f32_16x16x32_bf16(vfb, pf1, oacc[f], 0, 0, 0);
        }
        __builtin_amdgcn_s_setprio(0);

        __syncthreads();   // staging of buf^1 complete; all reads of buf done
        buf ^= 1;
    }

    // epilogue: O^T layout -> lane (g,fr): q = qt+fr, d = f*16+4g+r
    const float inv = 1.0f / lrow;
    const size_t obase = ((size_t)nb * SEQ + qt + fr) * DM + h * HDIM;
#pragma unroll
    for (int f = 0; f < 8; ++f) {
        uint2v v;
        v[0] = pk2bf(oacc[f][0] * inv, oacc[f][1] * inv);
        v[1] = pk2bf(oacc[f][2] * inv, oacc[f][3] * inv);
        *(uint2v*)(O + obase + f * 16 + 4 * g) = v;
    }
}

extern "C" void kernel_launch(void* const* d_in, const int* in_sizes, int n_in,
                              void* d_out, int out_size, void* d_ws, size_t ws_size,
                              hipStream_t stream) {
    const float* x    = (const float*)d_in[0];   // [2,2048,2048]
    const float* pos  = (const float*)d_in[1];   // [2,2048,128]
    const float* wqkv = (const float*)d_in[2];   // [6144,2048]
    const float* wo   = (const float*)d_in[3];   // [2048,2048]
    float* out = (float*)d_out;

    const size_t HBUF = (size_t)NB * NHEAD * SEQ * HDIM;  // 8Mi elems = 16MiB
    unsigned short* qb   = (unsigned short*)d_ws;         // Q; later w_o bf16
    unsigned short* kbuf = qb + HBUF;
    unsigned short* vtb  = kbuf + HBUF;
    unsigned short* obx  = vtb + HBUF;        // x_bf16 during gemm1, then attn O
    unsigned short* wqkvbf = (unsigned short*)d_out;  // 24MiB scratch in d_out
                                              // (dead before gemm_m97 rewrites d_out)

    // 0) pre-convert x and w_qkv to bf16
    cvt_bf16<<<dim3(2048), 256, 0, stream>>>(x, obx, 1048576, wqkv, wqkvbf, 1572864);
    // 1) QKV projection (bf16 x bf16, gload_lds) + RoPE + head scatter.
    //    CHALF=1 (r14 col-group split regressed: FETCH 102->155MB).
    gemm_m97<1, 6, 1><<<dim3(1536), 256, 0, stream>>>(obx, wqkvbf, 2048, qb, kbuf, vtb, pos, nullptr);
    // 2) causal flash attention (KVBLK=64, 64-row tiles, 1024 blocks)
    attn_k<<<dim3(1024), 256, 0, stream>>>(qb, kbuf, vtb, obx);
    // 3) convert w_o -> bf16 into qb (dead after attn)
    cvt_bf16<<<dim3(512), 256, 0, stream>>>(wo, qb, 524288, wo, qb, 0);
    // 4) output projection (bf16 x bf16) -> f32 d_out.
    gemm_m97<0, 2, 1><<<dim3(512), 256, 0, stream>>>(obx, qb, 2048, nullptr, nullptr, nullptr, nullptr, out);
}